// Round 1
// baseline (630.014 us; speedup 1.0000x reference)
//
#include <hip/hip_runtime.h>

typedef __bf16 bf16x8 __attribute__((ext_vector_type(8)));
typedef float f32x16 __attribute__((ext_vector_type(16)));

__device__ __forceinline__ unsigned short f2bf(float f) {
    unsigned int u = __float_as_uint(f);
    u += 0x7FFFu + ((u >> 16) & 1u);   // round-to-nearest-even
    return (unsigned short)(u >> 16);
}

// ---------------- Kernel A: clusters fp32 -> bf16 (+ c_sq) ----------------
// 1024 rows x 512. One wave per row; 256 blocks x 256 threads.
__global__ __launch_bounds__(256) void prep_clusters(
    const float* __restrict__ cl, unsigned short* __restrict__ cbf,
    float* __restrict__ csq) {
    const int row  = blockIdx.x * 4 + (threadIdx.x >> 6);
    const int lane = threadIdx.x & 63;
    const float4* cg = (const float4*)(cl + ((size_t)row << 9));
    float ssq = 0.f;
#pragma unroll
    for (int i = 0; i < 2; ++i) {
        float4 v = cg[lane + 64 * i];
        ssq += v.x * v.x + v.y * v.y + v.z * v.z + v.w * v.w;
        ushort4 h;
        h.x = f2bf(v.x); h.y = f2bf(v.y); h.z = f2bf(v.z); h.w = f2bf(v.w);
        *(ushort4*)(cbf + ((size_t)row << 9) + (size_t)(lane + 64 * i) * 4) = h;
    }
#pragma unroll
    for (int off = 32; off >= 1; off >>= 1) ssq += __shfl_xor(ssq, off);
    if (lane == 0) csq[row] = ssq;
}

// ---------------- Kernel B: fused GEMM + q + row-normalize ----------------
// Block: 1024 threads (16 waves). BM=64 rows, BN=1024 (ALL clusters) -> row
// sums are block-local. Wave w covers cols [64w, 64w+64) as 2 N-tiles of 32.
// MFMA 32x32x16 bf16, 2x2 tiles/wave (64 acc VGPRs). A from LDS (x tile,
// staged fp32->bf16 in 2 D-chunks of 256), B direct from L2 (clusters bf16,
// 1 MB resident). K-loop has NO barriers.
#define LDA 272   // 256 + 16 ushorts: 544 B row stride, 16B-aligned, 8 dw/bank

__global__ __launch_bounds__(1024, 4) void soft_assign(
    const float* __restrict__ x, const unsigned short* __restrict__ cbf,
    const float* __restrict__ csq, float* __restrict__ out) {
    __shared__ unsigned short xs[64 * LDA];   // 34816 B
    __shared__ float part[64 * 32];           // 8192 B  row-sum partials
    __shared__ float xsq[64];
    __shared__ float inv[64];

    const int t    = threadIdx.x;
    const int lane = t & 63;
    const int w    = t >> 6;      // wave 0..15
    const int l31  = lane & 31;
    const int half = lane >> 5;   // k-half for A/B fragments
    const int rb   = blockIdx.x;  // 64-row block

    part[t] = 0.f;
    part[t + 1024] = 0.f;

    const int col0   = w * 64 + l31;       // N-tile 0 column
    const float csq0 = csq[col0];
    const float csq1 = csq[col0 + 32];

    f32x16 c00, c01, c10, c11;
#pragma unroll
    for (int i = 0; i < 16; ++i) { c00[i] = 0.f; c01[i] = 0.f; c10[i] = 0.f; c11[i] = 0.f; }

    // staging roles: 16 threads per row
    const int srow = t >> 4;   // 0..63
    const int sj   = t & 15;
    float ssq = 0.f;

    const unsigned short* b0base = cbf + (size_t)col0 * 512 + half * 8;
    const unsigned short* b1base = b0base + 32 * 512;
    const unsigned short* a0base = xs + l31 * LDA + half * 8;         // rows 0..31
    const unsigned short* a1base = a0base + 32 * LDA;                 // rows 32..63

#pragma unroll 1
    for (int ch = 0; ch < 2; ++ch) {
        if (ch) __syncthreads();   // previous chunk's K-loop done before restage
        {
            const float4* xg = (const float4*)(x + (size_t)(rb * 64 + srow) * 512 + ch * 256);
#pragma unroll
            for (int i = 0; i < 4; ++i) {
                float4 v = xg[sj + 16 * i];
                ssq += v.x * v.x + v.y * v.y + v.z * v.z + v.w * v.w;
                ushort4 h;
                h.x = f2bf(v.x); h.y = f2bf(v.y); h.z = f2bf(v.z); h.w = f2bf(v.w);
                *(ushort4*)(xs + srow * LDA + (sj + 16 * i) * 4) = h;
            }
        }
        if (ch == 1) {   // finalize ||x||^2 (fp32, full D)
            float s2 = ssq;
#pragma unroll
            for (int off = 8; off >= 1; off >>= 1) s2 += __shfl_xor(s2, off);
            if (sj == 0) xsq[srow] = s2;
        }
        __syncthreads();

        // ---- K loop: 16 steps of K=16, barrier-free ----
        const unsigned short* bp0 = b0base + ch * 256;
        const unsigned short* bp1 = b1base + ch * 256;
        bf16x8 b0 = *(const bf16x8*)bp0;
        bf16x8 b1 = *(const bf16x8*)bp1;
#pragma unroll 4
        for (int s = 0; s < 16; ++s) {
            const int nx = ((s + 1) & 15) * 16;                 // wrap: harmless reload
            bf16x8 b0n = *(const bf16x8*)(bp0 + nx);            // depth-1 prefetch (L2)
            bf16x8 b1n = *(const bf16x8*)(bp1 + nx);
            bf16x8 a0 = *(const bf16x8*)(a0base + s * 16);
            bf16x8 a1 = *(const bf16x8*)(a1base + s * 16);
            c00 = __builtin_amdgcn_mfma_f32_32x32x16_bf16(a0, b0, c00, 0, 0, 0);
            c01 = __builtin_amdgcn_mfma_f32_32x32x16_bf16(a0, b1, c01, 0, 0, 0);
            c10 = __builtin_amdgcn_mfma_f32_32x32x16_bf16(a1, b0, c10, 0, 0, 0);
            c11 = __builtin_amdgcn_mfma_f32_32x32x16_bf16(a1, b1, c11, 0, 0, 0);
            b0 = b0n; b1 = b1n;
        }
    }

    // ---- epilogue: q = 1/(1+max(d,0)), accumulate row sums ----
    // C/D layout 32x32: col = lane&31, row = (reg&3) + 8*(reg>>2) + 4*(lane>>5)
#pragma unroll
    for (int r = 0; r < 16; ++r) {
        const int rl0 = (r & 3) + 8 * (r >> 2) + 4 * half;   // mt=0 local row
        const float x0 = xsq[rl0];
        const float x1 = xsq[rl0 + 32];
        float q00 = __builtin_amdgcn_rcpf(1.f + fmaxf(x0 + csq0 - 2.f * c00[r], 0.f));
        float q01 = __builtin_amdgcn_rcpf(1.f + fmaxf(x0 + csq1 - 2.f * c01[r], 0.f));
        float q10 = __builtin_amdgcn_rcpf(1.f + fmaxf(x1 + csq0 - 2.f * c10[r], 0.f));
        float q11 = __builtin_amdgcn_rcpf(1.f + fmaxf(x1 + csq1 - 2.f * c11[r], 0.f));
        c00[r] = q00; c01[r] = q01; c10[r] = q10; c11[r] = q11;
        atomicAdd(&part[rl0 * 32 + l31], q00 + q01);          // ds_add_f32, bank=l31
        atomicAdd(&part[(rl0 + 32) * 32 + l31], q10 + q11);
    }
    __syncthreads();
    if (t < 64) {
        float s = 0.f;
#pragma unroll
        for (int c = 0; c < 32; ++c) s += part[t * 32 + c];
        inv[t] = __builtin_amdgcn_rcpf(s);
    }
    __syncthreads();

    float* og = out + (size_t)rb * 64 * 1024;
#pragma unroll
    for (int r = 0; r < 16; ++r) {
        const int rl0 = (r & 3) + 8 * (r >> 2) + 4 * half;
        const float i0 = inv[rl0];
        const float i1 = inv[rl0 + 32];
        og[(size_t)rl0 * 1024 + col0]             = c00[r] * i0;
        og[(size_t)rl0 * 1024 + col0 + 32]        = c01[r] * i0;
        og[(size_t)(rl0 + 32) * 1024 + col0]      = c10[r] * i1;
        og[(size_t)(rl0 + 32) * 1024 + col0 + 32] = c11[r] * i1;
    }
}

extern "C" void kernel_launch(void* const* d_in, const int* in_sizes, int n_in,
                              void* d_out, int out_size, void* d_ws, size_t ws_size,
                              hipStream_t stream) {
    const float* x  = (const float*)d_in[0];   // (65536, 512) fp32
    const float* cl = (const float*)d_in[1];   // (1024, 512) fp32
    float* out = (float*)d_out;                // (65536, 1024) fp32

    unsigned short* cbf = (unsigned short*)d_ws;                       // 1 MB bf16 clusters
    float* csq = (float*)((char*)d_ws + (size_t)1024 * 512 * 2);       // 4 KB ||c||^2

    prep_clusters<<<256, 256, 0, stream>>>(cl, cbf, csq);
    soft_assign<<<1024, 1024, 0, stream>>>(x, cbf, csq, out);
}

// Round 2
// 570.147 us; speedup vs baseline: 1.1050x; 1.1050x over previous
//
#include <hip/hip_runtime.h>

typedef __bf16 bf16x8 __attribute__((ext_vector_type(8)));
typedef float f32x16 __attribute__((ext_vector_type(16)));
typedef unsigned short ushort8 __attribute__((ext_vector_type(8)));

__device__ __forceinline__ unsigned short f2bf(float f) {
    unsigned int u = __float_as_uint(f);
    u += 0x7FFFu + ((u >> 16) & 1u);   // round-to-nearest-even
    return (unsigned short)(u >> 16);
}

// ---------------- Kernel A: pack clusters fp32 -> bf16 fragment order ------
// Packed layout: cbf[((T*32 + s)*64 + h*32 + n)*8 + j] = cl[T*32+n][s*16+h*8+j]
// so a wave's B-fragment load (tile T, k-step s) is 64 lanes x 16 B contiguous.
__global__ __launch_bounds__(256) void prep_clusters(
    const float* __restrict__ cl, unsigned short* __restrict__ cbf,
    float* __restrict__ csq) {
    const int row  = blockIdx.x * 4 + (threadIdx.x >> 6);   // 0..1023
    const int lane = threadIdx.x & 63;                      // handles d = 8*lane..+8
    const float4* cg = (const float4*)(cl + ((size_t)row << 9) + lane * 8);
    float4 v0 = cg[0], v1 = cg[1];
    float ssq = v0.x*v0.x + v0.y*v0.y + v0.z*v0.z + v0.w*v0.w
              + v1.x*v1.x + v1.y*v1.y + v1.z*v1.z + v1.w*v1.w;
    ushort8 h;
    h[0]=f2bf(v0.x); h[1]=f2bf(v0.y); h[2]=f2bf(v0.z); h[3]=f2bf(v0.w);
    h[4]=f2bf(v1.x); h[5]=f2bf(v1.y); h[6]=f2bf(v1.z); h[7]=f2bf(v1.w);
    const int n = row & 31, T = row >> 5;
    const int s = lane >> 1, hh = lane & 1;                 // d0=8*lane -> s=lane/2, half=lane&1
    *(ushort8*)(cbf + (size_t)((T * 32 + s) * 64 + hh * 32 + n) * 8) = h;
#pragma unroll
    for (int off = 32; off >= 1; off >>= 1) ssq += __shfl_xor(ssq, off);
    if (lane == 0) csq[row] = ssq;
}

// ---------------- Kernel B: fused GEMM + q + row-normalize ----------------
// Block: 1024 threads (16 waves). BM=64 rows, BN=1024 (ALL clusters).
// A staged fp32->bf16 into LDS in MFMA fragment order, 2 chunks of D=256.
// B streamed from L2 in fragment order (contiguous 1 KB per wave-load),
// depth-2 register prefetch. K-loop barrier-free.
__global__ __launch_bounds__(1024, 4) void soft_assign(
    const float* __restrict__ x, const unsigned short* __restrict__ cbf,
    const float* __restrict__ csq, float* __restrict__ out) {
    __shared__ unsigned short xs[2048 * 8];   // 32 KB: [mt(2)][s(16)][lane(64)][8]
    __shared__ float part[64 * 32];           // 8 KB row-sum partials
    __shared__ float xsq[64];
    __shared__ float inv[64];

    const int t    = threadIdx.x;
    const int lane = t & 63;
    const int w    = t >> 6;      // wave 0..15
    const int l31  = lane & 31;
    const int half = lane >> 5;
    const int rb   = blockIdx.x;  // 64-row block

    part[t] = 0.f;
    part[t + 1024] = 0.f;
    if (t < 64) xsq[t] = 0.f;

    const int col0   = w * 64 + l31;
    const float csq0 = csq[col0];
    const float csq1 = csq[col0 + 32];

    f32x16 c00, c01, c10, c11;
#pragma unroll
    for (int i = 0; i < 16; ++i) { c00[i] = 0.f; c01[i] = 0.f; c10[i] = 0.f; c11[i] = 0.f; }

    // B fragment bases (packed): tile T0=2w, T1=2w+1; per-step stride = 64*8 ushorts
    const unsigned short* bT0 = cbf + ((size_t)(2 * w) * 32 * 64 + lane) * 8;
    const unsigned short* bT1 = cbf + ((size_t)(2 * w + 1) * 32 * 64 + lane) * 8;
    const unsigned short* aB  = xs + lane * 8;

    // preload B for global steps 0,1
    bf16x8 b0c = *(const bf16x8*)(bT0);
    bf16x8 b1c = *(const bf16x8*)(bT1);
    bf16x8 b0n = *(const bf16x8*)(bT0 + 512);
    bf16x8 b1n = *(const bf16x8*)(bT1 + 512);

#pragma unroll 1
    for (int ch = 0; ch < 2; ++ch) {
        if (ch) __syncthreads();   // previous chunk's K-loop done before restage
        // ---- stage A chunk: 2048 groups of 8 elems; thread t -> groups 2t, 2t+1
#pragma unroll
        for (int i = 0; i < 2; ++i) {
            const int g  = 2 * t + i;
            const int l  = g & 63;
            const int sl = (g >> 6) & 15;
            const int mt = g >> 10;
            const int row = mt * 32 + (l & 31);
            const int d0  = ch * 256 + sl * 16 + (l >> 5) * 8;
            const float4* xg = (const float4*)(x + (size_t)(rb * 64 + row) * 512 + d0);
            float4 v0 = xg[0], v1 = xg[1];
            ushort8 h;
            h[0]=f2bf(v0.x); h[1]=f2bf(v0.y); h[2]=f2bf(v0.z); h[3]=f2bf(v0.w);
            h[4]=f2bf(v1.x); h[5]=f2bf(v1.y); h[6]=f2bf(v1.z); h[7]=f2bf(v1.w);
            *(ushort8*)(xs + (size_t)g * 8) = h;
            float ss = v0.x*v0.x + v0.y*v0.y + v0.z*v0.z + v0.w*v0.w
                     + v1.x*v1.x + v1.y*v1.y + v1.z*v1.z + v1.w*v1.w;
            atomicAdd(&xsq[row], ss);   // fp32 ||x||^2, 2-way LDS atomic
        }
        __syncthreads();

        // ---- K loop: 16 local steps (global step sg = ch*16 + sl), barrier-free
#pragma unroll 1
        for (int sl = 0; sl < 16; sl += 2) {
            const int sg  = ch * 16 + sl;
            const int sp2 = (sg + 2) & 31;   // wrap at end: harmless reload
            const int sp3 = (sg + 3) & 31;
            bf16x8 p0 = *(const bf16x8*)(bT0 + sp2 * 512);
            bf16x8 p1 = *(const bf16x8*)(bT1 + sp2 * 512);
            bf16x8 q0 = *(const bf16x8*)(bT0 + sp3 * 512);
            bf16x8 q1 = *(const bf16x8*)(bT1 + sp3 * 512);
            bf16x8 a0 = *(const bf16x8*)(aB + (sl)     * 512);            // mt=0
            bf16x8 a1 = *(const bf16x8*)(aB + 8192 + (sl)     * 512);     // mt=1
            bf16x8 a2 = *(const bf16x8*)(aB + (sl + 1) * 512);
            bf16x8 a3 = *(const bf16x8*)(aB + 8192 + (sl + 1) * 512);
            c00 = __builtin_amdgcn_mfma_f32_32x32x16_bf16(a0, b0c, c00, 0, 0, 0);
            c01 = __builtin_amdgcn_mfma_f32_32x32x16_bf16(a0, b1c, c01, 0, 0, 0);
            c10 = __builtin_amdgcn_mfma_f32_32x32x16_bf16(a1, b0c, c10, 0, 0, 0);
            c11 = __builtin_amdgcn_mfma_f32_32x32x16_bf16(a1, b1c, c11, 0, 0, 0);
            c00 = __builtin_amdgcn_mfma_f32_32x32x16_bf16(a2, b0n, c00, 0, 0, 0);
            c01 = __builtin_amdgcn_mfma_f32_32x32x16_bf16(a2, b1n, c01, 0, 0, 0);
            c10 = __builtin_amdgcn_mfma_f32_32x32x16_bf16(a3, b0n, c10, 0, 0, 0);
            c11 = __builtin_amdgcn_mfma_f32_32x32x16_bf16(a3, b1n, c11, 0, 0, 0);
            b0c = p0; b1c = p1; b0n = q0; b1n = q1;
        }
    }

    // ---- epilogue: q = 1/(1+max(d,0)), accumulate row sums ----
    // C/D 32x32 layout: col = lane&31, row = (reg&3) + 8*(reg>>2) + 4*(lane>>5)
#pragma unroll
    for (int r = 0; r < 16; ++r) {
        const int rl0 = (r & 3) + 8 * (r >> 2) + 4 * half;
        const float x0 = xsq[rl0];
        const float x1 = xsq[rl0 + 32];
        float q00 = __builtin_amdgcn_rcpf(1.f + fmaxf(x0 + csq0 - 2.f * c00[r], 0.f));
        float q01 = __builtin_amdgcn_rcpf(1.f + fmaxf(x0 + csq1 - 2.f * c01[r], 0.f));
        float q10 = __builtin_amdgcn_rcpf(1.f + fmaxf(x1 + csq0 - 2.f * c10[r], 0.f));
        float q11 = __builtin_amdgcn_rcpf(1.f + fmaxf(x1 + csq1 - 2.f * c11[r], 0.f));
        c00[r] = q00; c01[r] = q01; c10[r] = q10; c11[r] = q11;
        atomicAdd(&part[rl0 * 32 + l31], q00 + q01);          // bank = l31: 2-way, free
        atomicAdd(&part[(rl0 + 32) * 32 + l31], q10 + q11);
    }
    __syncthreads();
    if (t < 64) {
        float s = 0.f;
#pragma unroll
        for (int c = 0; c < 32; ++c) s += part[t * 32 + ((c + t) & 31)];  // rotated: no bank conflict
        inv[t] = __builtin_amdgcn_rcpf(s);
    }
    __syncthreads();

    float* og = out + (size_t)rb * 64 * 1024;
#pragma unroll
    for (int r = 0; r < 16; ++r) {
        const int rl0 = (r & 3) + 8 * (r >> 2) + 4 * half;
        const float i0 = inv[rl0];
        const float i1 = inv[rl0 + 32];
        og[(size_t)rl0 * 1024 + col0]             = c00[r] * i0;
        og[(size_t)rl0 * 1024 + col0 + 32]        = c01[r] * i0;
        og[(size_t)(rl0 + 32) * 1024 + col0]      = c10[r] * i1;
        og[(size_t)(rl0 + 32) * 1024 + col0 + 32] = c11[r] * i1;
    }
}

extern "C" void kernel_launch(void* const* d_in, const int* in_sizes, int n_in,
                              void* d_out, int out_size, void* d_ws, size_t ws_size,
                              hipStream_t stream) {
    const float* x  = (const float*)d_in[0];   // (65536, 512) fp32
    const float* cl = (const float*)d_in[1];   // (1024, 512) fp32
    float* out = (float*)d_out;                // (65536, 1024) fp32

    unsigned short* cbf = (unsigned short*)d_ws;                       // 1 MB packed bf16
    float* csq = (float*)((char*)d_ws + (size_t)1024 * 512 * 2);       // 4 KB ||c||^2

    prep_clusters<<<256, 256, 0, stream>>>(cl, cbf, csq);
    soft_assign<<<1024, 1024, 0, stream>>>(x, cbf, csq, out);
}